// Round 8
// baseline (136.029 us; speedup 1.0000x reference)
//
#include <hip/hip_runtime.h>
#include <hip/hip_bf16.h>
#include <math.h>

#define B_ 4096
#define F_ 64
#define A_ 8
#define U_ 32

typedef float f32x4 __attribute__((ext_vector_type(4)));
typedef short bf16x8 __attribute__((ext_vector_type(8)));

// ws layout (8 MB + 1 KB):
//   SPART [0, 8 MB): 512 slots x 16 KB: bf16-pair partials, slot = (a*32+bt)*2+h,
//     dword [row][c]    = pk(S(f=c),    S(f=32+c))
//     dword [row][16+c] = pk(S(f=16+c), S(f=48+c))   row in [0,128), c in [0,16)
//   FLAG [8 MB, +1 KB): one dword per pair (a*32+bt); poison-safe atomicExch protocol
#define SPART_OFF 0ull
#define FLAG_OFF  (8ull << 20)
#define WS_NEED   (FLAG_OFF + 1024ull)
#define TAGH(h)   (0x5EED0000u | (unsigned)(h))

static __device__ __forceinline__ unsigned int pk_bf16(float lo, float hi) {
    union { __hip_bfloat162 h2; unsigned int u; } cv;
    cv.h2 = __float22bfloat162_rn(make_float2(lo, hi));
    return cv.u;
}
static __device__ __forceinline__ float rb(float f) {   // fp32 -> bf16 -> fp32 (RNE)
    unsigned int u = __float_as_uint(f);
    u += 0x7FFFu + ((u >> 16) & 1u);
    return __uint_as_float(u & 0xFFFF0000u);
}
static __device__ __forceinline__ float b2f(unsigned int h16) {
    return __uint_as_float(h16 << 16);
}

// Block = (bt in [0,32): 128 rows, h in {0,1}: j-half, a): 4 waves x 32 rows/wave.
// In-block per-j frag prep (r7-proven layout math), 32-j loop, then non-blocking
// pairwise rendezvous: later-finishing block of each (bt,a) pair combines.
__global__ __launch_bounds__(256, 2)
void ife_half(const float* __restrict__ x,     // [B, F]
              const float* __restrict__ kern,  // [j=F, A, F, U]
              unsigned char* __restrict__ ws,
              float* __restrict__ out)         // [A, B, F]
{
    const int bx = blockIdx.x;                 // 0..63
    const int bt = bx >> 1, h = bx & 1;
    const int a = blockIdx.y, t = threadIdx.x;
    const int wv = t >> 6, lane = t & 63, q = lane >> 4, c = lane & 15;
    const int R0 = bt * 128;

    __shared__ float Xf[128][33];                           // rb-rounded x, my 32 j-cols
    __shared__ __align__(16) unsigned int Pbuf[4][2][16][20];
    __shared__ __align__(16) uint4 Kfr[2][4][64];           // dbuf K B-frags
    __shared__ __align__(16) uint4 Wfr[2][4][64];           // dbuf W B-frags
    __shared__ int sh_combine;

    // ---- X A-frags: 2 row-groups x 2 k-chunks ----
    bf16x8 Xh[2][2];
    #pragma unroll
    for (int rg = 0; rg < 2; ++rg) {
        const float* xr = x + (size_t)(R0 + wv * 32 + rg * 16 + c) * F_;
        #pragma unroll
        for (int kc = 0; kc < 2; ++kc) {
            const float4 va = *(const float4*)&xr[kc * 32 + q * 8];
            const float4 vb = *(const float4*)&xr[kc * 32 + q * 8 + 4];
            union { unsigned int u[4]; bf16x8 v; } H;
            H.u[0] = pk_bf16(va.x, va.y);
            H.u[1] = pk_bf16(va.z, va.w);
            H.u[2] = pk_bf16(vb.x, vb.y);
            H.u[3] = pk_bf16(vb.z, vb.w);
            Xh[rg][kc] = H.v;
        }
    }
    // ---- Xf: 128 rows x my j-half columns (rb-rounded) ----
    {
        const int row = t >> 1, cs = (t & 1) * 16;
        const float* xsrc = x + (size_t)(R0 + row) * F_ + h * 32 + cs;
        #pragma unroll
        for (int i = 0; i < 16; i += 4) {
            const float4 v = *(const float4*)&xsrc[i];
            Xf[row][cs + i]     = rb(v.x);
            Xf[row][cs + i + 1] = rb(v.y);
            Xf[row][cs + i + 2] = rb(v.z);
            Xf[row][cs + i + 3] = rb(v.w);
        }
    }

    // prep roles (r7-proven): thread owns frag id = wv, lane slot = lane
    const int kcP = wv >> 1, utP = wv & 1;
    float4 w0, w1; float kr[8]; float2 kdn;
    auto PREP_LOAD = [&](int jl) {
        const int jg = h * 32 + jl;
        const float* kj = kern + ((size_t)jg * A_ + a) * (F_ * U_);
        const float* wrow = kj + (wv * 16 + c) * U_ + q * 8;
        w0 = *(const float4*)wrow;
        w1 = *(const float4*)(wrow + 4);
        const float* kcol = kj + (kcP * 32 + q * 8) * U_ + utP * 16 + c;
        #pragma unroll
        for (int i = 0; i < 8; ++i) kr[i] = kcol[i * U_];
        kdn.x = kj[jg * U_ + c];
        kdn.y = kj[jg * U_ + 16 + c];
    };
    auto PREP_STORE = [&](int pb) {
        uint4 kw, ww;
        kw.x = pk_bf16(kr[0], kr[1]);
        kw.y = pk_bf16(kr[2], kr[3]);
        kw.z = pk_bf16(kr[4], kr[5]);
        kw.w = pk_bf16(kr[6], kr[7]);
        ww.x = pk_bf16(__expf(2.f * w0.x), __expf(2.f * w0.y));
        ww.y = pk_bf16(__expf(2.f * w0.z), __expf(2.f * w0.w));
        ww.z = pk_bf16(__expf(2.f * w1.x), __expf(2.f * w1.y));
        ww.w = pk_bf16(__expf(2.f * w1.z), __expf(2.f * w1.w));
        Kfr[pb][wv][lane] = kw;
        Wfr[pb][wv][lane] = ww;
    };

    PREP_LOAD(0);
    PREP_STORE(0);
    float2 kdc = kdn;
    __syncthreads();

    const unsigned int psel = (q < 2) ? 0x05040100u : 0x07060302u;
    union { unsigned int u[4]; bf16x8 v; } oc;
    oc.u[0] = 0x3F803F80u; oc.u[1] = 0x3F803F80u; oc.u[2] = 0x3F803F80u; oc.u[3] = 0x3F803F80u;
    const bf16x8 ONES = oc.v;
    const f32x4 vzero = (f32x4){0.f, 0.f, 0.f, 0.f};

    f32x4 S[2][4];
    #pragma unroll
    for (int rg = 0; rg < 2; ++rg)
        #pragma unroll
        for (int ft = 0; ft < 4; ++ft) S[rg][ft] = vzero;

    for (int jl = 0; jl < 32; ++jl) {
        const int buf = jl & 1;
        PREP_LOAD((jl + 1 < 32) ? (jl + 1) : 31);

        union { uint4 u; bf16x8 v; } K[4], W[4];
        #pragma unroll
        for (int i = 0; i < 4; ++i) {
            K[i].u = Kfr[buf][i][lane];
            W[i].u = Wfr[buf][i][lane];
        }

        f32x4 ZA[2], ZB[2];
        #pragma unroll
        for (int rg = 0; rg < 2; ++rg) {
            f32x4 za = vzero, zb = vzero;
            za = __builtin_amdgcn_mfma_f32_16x16x32_bf16(Xh[rg][0], K[0].v, za, 0, 0, 0);
            za = __builtin_amdgcn_mfma_f32_16x16x32_bf16(Xh[rg][1], K[2].v, za, 0, 0, 0);
            zb = __builtin_amdgcn_mfma_f32_16x16x32_bf16(Xh[rg][0], K[1].v, zb, 0, 0, 0);
            zb = __builtin_amdgcn_mfma_f32_16x16x32_bf16(Xh[rg][1], K[3].v, zb, 0, 0, 0);
            ZA[rg] = za; ZB[rg] = zb;
        }

        const float kd0 = rb(kdc.x), kd1 = rb(kdc.y);
        #pragma unroll
        for (int rg = 0; rg < 2; ++rg)
            #pragma unroll
            for (int r = 0; r < 4; ++r) {
                const float xj = Xf[wv * 32 + rg * 16 + q * 4 + r][jl];
                const float e0 = __expf(ZA[rg][r] - xj * kd0);
                const float e1 = __expf(ZB[rg][r] - xj * kd1);
                Pbuf[wv][rg][q * 4 + r][c] = pk_bf16(e0, e1);
            }
        asm volatile("s_waitcnt lgkmcnt(0)" ::: "memory");
        union { unsigned int u[4]; bf16x8 v; } E[2];
        #pragma unroll
        for (int rg = 0; rg < 2; ++rg) {
            const uint4 pa = *(const uint4*)&Pbuf[wv][rg][c][(q & 1) * 8];
            const uint4 pb = *(const uint4*)&Pbuf[wv][rg][c][(q & 1) * 8 + 4];
            E[rg].u[0] = __builtin_amdgcn_perm(pa.y, pa.x, psel);
            E[rg].u[1] = __builtin_amdgcn_perm(pa.w, pa.z, psel);
            E[rg].u[2] = __builtin_amdgcn_perm(pb.y, pb.x, psel);
            E[rg].u[3] = __builtin_amdgcn_perm(pb.w, pb.z, psel);
        }
        #pragma unroll
        for (int rg = 0; rg < 2; ++rg) {
            const f32x4 sv = __builtin_amdgcn_mfma_f32_16x16x32_bf16(E[rg].v, ONES, vzero, 0, 0, 0);
            f32x4 D0 = __builtin_amdgcn_mfma_f32_16x16x32_bf16(E[rg].v, W[0].v, vzero, 0, 0, 0);
            f32x4 D1 = __builtin_amdgcn_mfma_f32_16x16x32_bf16(E[rg].v, W[1].v, vzero, 0, 0, 0);
            f32x4 D2 = __builtin_amdgcn_mfma_f32_16x16x32_bf16(E[rg].v, W[2].v, vzero, 0, 0, 0);
            f32x4 D3 = __builtin_amdgcn_mfma_f32_16x16x32_bf16(E[rg].v, W[3].v, vzero, 0, 0, 0);
            #pragma unroll
            for (int r = 0; r < 4; ++r) {
                const float inv = __builtin_amdgcn_rcpf(sv[r]);
                S[rg][0][r] += D0[r] * inv;
                S[rg][1][r] += D1[r] * inv;
                S[rg][2][r] += D2[r] * inv;
                S[rg][3][r] += D3[r] * inv;
            }
        }

        PREP_STORE(buf ^ 1);
        __syncthreads();
        kdc = kdn;
    }

    // ---- store bf16 partials (scaled 1/64) to my slot ----
    const float sc = 1.f / 64.f;
    const int pair = a * 32 + bt;
    unsigned int* slot = (unsigned int*)(ws + SPART_OFF) + (size_t)(pair * 2 + h) * (128 * 32);
    #pragma unroll
    for (int rg = 0; rg < 2; ++rg)
        #pragma unroll
        for (int r = 0; r < 4; ++r) {
            const int lr2 = wv * 32 + rg * 16 + q * 4 + r;
            unsigned int* p = slot + lr2 * 32;
            p[c]      = pk_bf16(S[rg][0][r] * sc, S[rg][2][r] * sc);
            p[16 + c] = pk_bf16(S[rg][1][r] * sc, S[rg][3][r] * sc);
        }

    // ---- non-blocking pairwise rendezvous (poison-safe, no spin) ----
    __syncthreads();   // drains all waves' partial stores (vmcnt) before the fence
    if (t == 0) {
        __builtin_amdgcn_fence(__ATOMIC_RELEASE, "agent");
        unsigned int* flag = (unsigned int*)(ws + FLAG_OFF) + pair;
        const unsigned int old = __hip_atomic_exchange(flag, TAGH(h), __ATOMIC_ACQ_REL,
                                                       __HIP_MEMORY_SCOPE_AGENT);
        const int comb = (old == TAGH(h ^ 1)) ? 1 : 0;
        if (comb) __builtin_amdgcn_fence(__ATOMIC_ACQUIRE, "agent");
        sh_combine = comb;
    }
    __syncthreads();
    if (!sh_combine) return;   // partner (finishing later) combines

    // ---- combine: my fp32 regs + partner bf16 partial; softmax over f; store ----
    const unsigned int* pslot = (const unsigned int*)(ws + SPART_OFF)
                              + (size_t)(pair * 2 + (h ^ 1)) * (128 * 32);
    #pragma unroll
    for (int rg = 0; rg < 2; ++rg)
        #pragma unroll
        for (int r = 0; r < 4; ++r) {
            const int lr2 = wv * 32 + rg * 16 + q * 4 + r;
            const unsigned int m0 = pslot[lr2 * 32 + c];
            const unsigned int m1 = pslot[lr2 * 32 + 16 + c];
            const float v0 = S[rg][0][r] * sc + b2f(m0 & 0xFFFFu);
            const float v1 = S[rg][1][r] * sc + b2f(m1 & 0xFFFFu);
            const float v2 = S[rg][2][r] * sc + b2f(m0 >> 16);
            const float v3 = S[rg][3][r] * sc + b2f(m1 >> 16);
            const float e0 = __expf(v0), e1 = __expf(v1);
            const float e2 = __expf(v2), e3 = __expf(v3);
            float s = e0 + e1 + e2 + e3;
            s += __shfl_xor(s, 1);
            s += __shfl_xor(s, 2);
            s += __shfl_xor(s, 4);
            s += __shfl_xor(s, 8);
            const float inv = 1.f / s;
            const int row = R0 + lr2;
            float* o = out + ((size_t)a * B_ + row) * F_ + c;
            o[0]  = e0 * inv;
            o[16] = e1 * inv;
            o[32] = e2 * inv;
            o[48] = e3 * inv;
        }
}

// ================= fallback (r7 proven, used only if ws too small) =================
__global__ __launch_bounds__(256, 2)
void ife_onepass(const float* __restrict__ x, const float* __restrict__ kern,
                 float* __restrict__ out)
{
    const int a = blockIdx.y, bt = blockIdx.x, t = threadIdx.x;
    const int wv = t >> 6, lane = t & 63, q = lane >> 4, c = lane & 15;
    __shared__ float Xf[64][66];
    __shared__ __align__(16) unsigned int Pbuf[4][16][20];
    __shared__ __align__(16) uint4 Kfr[2][4][64];
    __shared__ __align__(16) uint4 Wfr[2][4][64];

    bf16x8 Xh[2];
    {
        const float* xr = x + (size_t)(bt * 64 + wv * 16 + c) * F_;
        #pragma unroll
        for (int kc = 0; kc < 2; ++kc) {
            const float4 va = *(const float4*)&xr[kc * 32 + q * 8];
            const float4 vb = *(const float4*)&xr[kc * 32 + q * 8 + 4];
            union { unsigned int u[4]; bf16x8 v; } H;
            H.u[0] = pk_bf16(va.x, va.y);
            H.u[1] = pk_bf16(va.z, va.w);
            H.u[2] = pk_bf16(vb.x, vb.y);
            H.u[3] = pk_bf16(vb.z, vb.w);
            Xh[kc] = H.v;
        }
    }
    {
        const int row = t >> 2, cb = (t & 3) * 16;
        const float* xsrc = x + (size_t)(bt * 64 + row) * F_ + cb;
        #pragma unroll
        for (int i = 0; i < 16; i += 4) {
            const float4 v = *(const float4*)&xsrc[i];
            Xf[row][cb + i]     = rb(v.x);
            Xf[row][cb + i + 1] = rb(v.y);
            Xf[row][cb + i + 2] = rb(v.z);
            Xf[row][cb + i + 3] = rb(v.w);
        }
    }
    const int kcP = wv >> 1, utP = wv & 1;
    float4 w0, w1; float kr[8]; float2 kdn;
    auto PREP_LOAD = [&](int jn) {
        const float* kj = kern + ((size_t)jn * A_ + a) * (F_ * U_);
        const float* wrow = kj + (wv * 16 + c) * U_ + q * 8;
        w0 = *(const float4*)wrow;
        w1 = *(const float4*)(wrow + 4);
        const float* kcol = kj + (kcP * 32 + q * 8) * U_ + utP * 16 + c;
        #pragma unroll
        for (int i = 0; i < 8; ++i) kr[i] = kcol[i * U_];
        kdn.x = kj[jn * U_ + c];
        kdn.y = kj[jn * U_ + 16 + c];
    };
    auto PREP_STORE = [&](int pb) {
        uint4 kw, ww;
        kw.x = pk_bf16(kr[0], kr[1]); kw.y = pk_bf16(kr[2], kr[3]);
        kw.z = pk_bf16(kr[4], kr[5]); kw.w = pk_bf16(kr[6], kr[7]);
        ww.x = pk_bf16(__expf(2.f * w0.x), __expf(2.f * w0.y));
        ww.y = pk_bf16(__expf(2.f * w0.z), __expf(2.f * w0.w));
        ww.z = pk_bf16(__expf(2.f * w1.x), __expf(2.f * w1.y));
        ww.w = pk_bf16(__expf(2.f * w1.z), __expf(2.f * w1.w));
        Kfr[pb][wv][lane] = kw;
        Wfr[pb][wv][lane] = ww;
    };
    PREP_LOAD(0); PREP_STORE(0);
    float2 kdc = kdn;
    __syncthreads();
    const unsigned int psel = (q < 2) ? 0x05040100u : 0x07060302u;
    union { unsigned int u[4]; bf16x8 v; } oc;
    oc.u[0] = 0x3F803F80u; oc.u[1] = 0x3F803F80u; oc.u[2] = 0x3F803F80u; oc.u[3] = 0x3F803F80u;
    const bf16x8 ONES = oc.v;
    const f32x4 vzero = (f32x4){0.f, 0.f, 0.f, 0.f};
    f32x4 S0 = vzero, S1 = vzero, S2 = vzero, S3 = vzero;
    for (int j = 0; j < 64; ++j) {
        const int buf = j & 1;
        PREP_LOAD((j + 1 < 64) ? (j + 1) : 63);
        union { uint4 u; bf16x8 v; } K[4], W[4];
        #pragma unroll
        for (int i = 0; i < 4; ++i) { K[i].u = Kfr[buf][i][lane]; W[i].u = Wfr[buf][i][lane]; }
        f32x4 ZA = vzero, ZB = vzero;
        ZA = __builtin_amdgcn_mfma_f32_16x16x32_bf16(Xh[0], K[0].v, ZA, 0, 0, 0);
        ZA = __builtin_amdgcn_mfma_f32_16x16x32_bf16(Xh[1], K[2].v, ZA, 0, 0, 0);
        ZB = __builtin_amdgcn_mfma_f32_16x16x32_bf16(Xh[0], K[1].v, ZB, 0, 0, 0);
        ZB = __builtin_amdgcn_mfma_f32_16x16x32_bf16(Xh[1], K[3].v, ZB, 0, 0, 0);
        const float kd0 = rb(kdc.x), kd1 = rb(kdc.y);
        #pragma unroll
        for (int r = 0; r < 4; ++r) {
            const float xj = Xf[wv * 16 + q * 4 + r][j];
            const float e0 = __expf(ZA[r] - xj * kd0);
            const float e1 = __expf(ZB[r] - xj * kd1);
            Pbuf[wv][q * 4 + r][c] = pk_bf16(e0, e1);
        }
        asm volatile("s_waitcnt lgkmcnt(0)" ::: "memory");
        union { unsigned int u[4]; bf16x8 v; } E;
        {
            const uint4 pa = *(const uint4*)&Pbuf[wv][c][(q & 1) * 8];
            const uint4 pb = *(const uint4*)&Pbuf[wv][c][(q & 1) * 8 + 4];
            E.u[0] = __builtin_amdgcn_perm(pa.y, pa.x, psel);
            E.u[1] = __builtin_amdgcn_perm(pa.w, pa.z, psel);
            E.u[2] = __builtin_amdgcn_perm(pb.y, pb.x, psel);
            E.u[3] = __builtin_amdgcn_perm(pb.w, pb.z, psel);
        }
        const f32x4 sv = __builtin_amdgcn_mfma_f32_16x16x32_bf16(E.v, ONES, vzero, 0, 0, 0);
        f32x4 D0 = __builtin_amdgcn_mfma_f32_16x16x32_bf16(E.v, W[0].v, vzero, 0, 0, 0);
        f32x4 D1 = __builtin_amdgcn_mfma_f32_16x16x32_bf16(E.v, W[1].v, vzero, 0, 0, 0);
        f32x4 D2 = __builtin_amdgcn_mfma_f32_16x16x32_bf16(E.v, W[2].v, vzero, 0, 0, 0);
        f32x4 D3 = __builtin_amdgcn_mfma_f32_16x16x32_bf16(E.v, W[3].v, vzero, 0, 0, 0);
        #pragma unroll
        for (int r = 0; r < 4; ++r) {
            const float inv = __builtin_amdgcn_rcpf(sv[r]);
            S0[r] += D0[r] * inv; S1[r] += D1[r] * inv;
            S2[r] += D2[r] * inv; S3[r] += D3[r] * inv;
        }
        PREP_STORE(buf ^ 1);
        __syncthreads();
        kdc = kdn;
    }
    const float sc = 1.f / 64.f;
    #pragma unroll
    for (int r = 0; r < 4; ++r) {
        const float e0 = __expf(S0[r] * sc), e1 = __expf(S1[r] * sc);
        const float e2 = __expf(S2[r] * sc), e3 = __expf(S3[r] * sc);
        float s = e0 + e1 + e2 + e3;
        s += __shfl_xor(s, 1); s += __shfl_xor(s, 2);
        s += __shfl_xor(s, 4); s += __shfl_xor(s, 8);
        const float inv = 1.f / s;
        const int bb = bt * 64 + wv * 16 + q * 4 + r;
        float* o = out + ((size_t)a * B_ + bb) * F_ + c;
        o[0] = e0 * inv; o[16] = e1 * inv; o[32] = e2 * inv; o[48] = e3 * inv;
    }
}

extern "C" void kernel_launch(void* const* d_in, const int* in_sizes, int n_in,
                              void* d_out, int out_size, void* d_ws, size_t ws_size,
                              hipStream_t stream) {
    (void)in_sizes; (void)n_in; (void)out_size;
    const float* x    = (const float*)d_in[0];   // [B, F]
    const float* kern = (const float*)d_in[1];   // [F, A, F, U]
    float* out        = (float*)d_out;           // [A, B, F]
    unsigned char* ws = (unsigned char*)d_ws;

    if (ws_size >= WS_NEED) {
        hipLaunchKernelGGL(ife_half, dim3(64, A_), dim3(256), 0, stream, x, kern, ws, out);
    } else {
        hipLaunchKernelGGL(ife_onepass, dim3(B_ / 64, A_), dim3(256), 0, stream, x, kern, out);
    }
}